// Round 8
// baseline (352.437 us; speedup 1.0000x reference)
//
#include <hip/hip_runtime.h>

#define D_MODEL 384
#define D_STATE 16
#define D_INNER 768
#define DT_RANK 24
#define NB 8
#define LSEQ 1024
#define NROWS (NB * LSEQ)             // 8192
#define DBC_N 56
#define SEG 16
#define NSEG 64

typedef unsigned short u16;
typedef __attribute__((ext_vector_type(8))) short bf16x8;
typedef __attribute__((ext_vector_type(4))) float f32x4;

__device__ __forceinline__ float silu(float x) { return x / (1.f + __expf(-x)); }

__device__ __forceinline__ u16 f2bf_rne(float v, float& hval) {
    unsigned u = __builtin_bit_cast(unsigned, v);
    unsigned h = (u + 0x7FFFu + ((u >> 16) & 1u)) >> 16;
    hval = __builtin_bit_cast(float, h << 16);
    return (u16)h;
}

__device__ __forceinline__ void split2(float v, u16& h, u16& l) {
    float hval, dummy;
    h = f2bf_rne(v, hval);
    l = f2bf_rne(v - hval, dummy);
}

// DPP move within rows of 16 lanes (VALU, no DS pipe). CTRL 0x120+N = row_ror:N.
template <int CTRL>
__device__ __forceinline__ float dpp_mov(float v) {
    return __builtin_bit_cast(float, __builtin_amdgcn_update_dpp(
        0, __builtin_bit_cast(int, v), CTRL, 0xf, 0xf, false));
}

// ---------------- weight split: f32 -> bf16 hi/lo
__global__ __launch_bounds__(256) void k_splitw(const float* __restrict__ src,
                                                u16* __restrict__ hi, u16* __restrict__ lo,
                                                int count) {
    const int i = blockIdx.x * 256 + threadIdx.x;
    if (i >= count) return;
    u16 h, l;
    split2(src[i], h, l);
    hi[i] = h; lo[i] = l;
}

// ---------------- x_proj weight split, padded 56 -> 64 rows (zeros)
__global__ __launch_bounds__(256) void k_splitw_pad(const float* __restrict__ src,
                                                    u16* __restrict__ hi, u16* __restrict__ lo) {
    const int i = blockIdx.x * 256 + threadIdx.x;   // over 64*768
    if (i >= 64 * 768) return;
    const int row = i / 768;
    u16 h = 0, l = 0;
    if (row < DBC_N) split2(src[i], h, l);
    hi[i] = h; lo[i] = l;
}

// ---------------- activation split + transpose: src [B][R][1024] f32 -> hi/lo [B*1024][R] bf16
__global__ __launch_bounds__(256) void k_splitT(const float* __restrict__ src,
                                                u16* __restrict__ hi, u16* __restrict__ lo,
                                                int R) {
    __shared__ float s[32][33];
    const int r0 = blockIdx.x * 32, c0 = blockIdx.y * 32, b = blockIdx.z;
    const int t = threadIdx.x;
    const int cc = t & 31, rr = t >> 5;
#pragma unroll
    for (int p = 0; p < 4; ++p)
        s[rr + p * 8][cc] = src[((size_t)b * R + r0 + rr + p * 8) * LSEQ + c0 + cc];
    __syncthreads();
    const int rr2 = t & 31, cc2 = t >> 5;
#pragma unroll
    for (int p = 0; p < 4; ++p) {
        const int c = cc2 + p * 8;
        u16 h, l;
        split2(s[rr2][c], h, l);
        const size_t idx = ((size_t)b * LSEQ + c0 + c) * R + r0 + rr2;
        hi[idx] = h; lo[idx] = l;
    }
}

// ---------------- split-bf16 MFMA GEMM (128x128 tile), 3 segments.
// MODE 0: in_proj epilogue; MODE 1: out_proj epilogue
template <int K, int MODE>
__global__ __launch_bounds__(256) void k_gemm(const u16* __restrict__ Ahi,
                                              const u16* __restrict__ Alo,
                                              const u16* __restrict__ Bhi,
                                              const u16* __restrict__ Blo,
                                              float* __restrict__ out0,
                                              float* __restrict__ out1) {
    constexpr int KT = K / 32;
    constexpr int NT = 3 * KT;
    __shared__ u16 lA[2][512 * 8];
    __shared__ u16 lB[2][512 * 8];
    const int tid = threadIdx.x;
    const int n0 = blockIdx.x * 128;
    const int m0 = blockIdx.y * 128;

    bf16x8 ra[2], rb[2];
    auto load_tile = [&](int t) {
        const int s = t / KT;
        const int ko = (t - s * KT) * 32;
        const u16* Ab = (s < 2) ? Ahi : Alo;
        const u16* Bb = (s == 1) ? Blo : Bhi;
#pragma unroll
        for (int i = 0; i < 2; ++i) {
            const int slot = tid + 256 * i;
            ra[i] = *reinterpret_cast<const bf16x8*>(
                Ab + (size_t)(m0 + (slot & 127)) * K + ko + (slot >> 7) * 8);
            rb[i] = *reinterpret_cast<const bf16x8*>(
                Bb + (size_t)(n0 + (slot & 127)) * K + ko + (slot >> 7) * 8);
        }
    };
    auto write_tile = [&](int buf) {
#pragma unroll
        for (int i = 0; i < 2; ++i) {
            const int slot = tid + 256 * i;
            *reinterpret_cast<bf16x8*>(&lA[buf][slot * 8]) = ra[i];
            *reinterpret_cast<bf16x8*>(&lB[buf][slot * 8]) = rb[i];
        }
    };

    load_tile(0);
    write_tile(0);
    load_tile(1);

    const int lane = tid & 63, w = tid >> 6;
    const int wm = w >> 1, wn = w & 1;
    const int fr = lane & 15, g = lane >> 4;
    const int abase = (g * 128 + wm * 64 + fr) * 8;
    const int bbase = (g * 128 + wn * 64 + fr) * 8;

    f32x4 acc[4][4] = {};
    for (int t = 0; t < NT; ++t) {
        const int cur = t & 1;
        __syncthreads();
        bf16x8 a[4], b[4];
#pragma unroll
        for (int mi = 0; mi < 4; ++mi)
            a[mi] = *reinterpret_cast<const bf16x8*>(&lA[cur][abase + mi * 128]);
#pragma unroll
        for (int ni = 0; ni < 4; ++ni)
            b[ni] = *reinterpret_cast<const bf16x8*>(&lB[cur][bbase + ni * 128]);
#pragma unroll
        for (int mi = 0; mi < 4; ++mi)
#pragma unroll
            for (int ni = 0; ni < 4; ++ni)
                acc[mi][ni] = __builtin_amdgcn_mfma_f32_16x16x32_bf16(
                    a[mi], b[ni], acc[mi][ni], 0, 0, 0);
        if (t + 1 < NT) {
            __syncthreads();
            write_tile(cur ^ 1);
            if (t + 2 < NT) load_tile(t + 2);
        }
    }

    const int b_idx = m0 >> 10;
    const int l0b = m0 & 1023;
    if (MODE == 0) {
        if (n0 < D_INNER) {
#pragma unroll
            for (int mi = 0; mi < 4; ++mi) {
#pragma unroll
                for (int ni = 0; ni < 4; ++ni) {
                    const int m = m0 + wm * 64 + mi * 16 + (lane >> 4) * 4;
                    const int n = n0 + wn * 64 + ni * 16 + (lane & 15);
#pragma unroll
                    for (int j = 0; j < 4; ++j)
                        out0[(size_t)(m + j) * D_INNER + n] = acc[mi][ni][j];
                }
            }
        } else {
#pragma unroll
            for (int mi = 0; mi < 4; ++mi) {
#pragma unroll
                for (int ni = 0; ni < 4; ++ni) {
                    const int l = l0b + wm * 64 + mi * 16 + (lane >> 4) * 4;
                    const int d = (n0 - D_INNER) + wn * 64 + ni * 16 + (lane & 15);
                    float4 v = make_float4(silu(acc[mi][ni][0]), silu(acc[mi][ni][1]),
                                           silu(acc[mi][ni][2]), silu(acc[mi][ni][3]));
                    *reinterpret_cast<float4*>(
                        &out1[((size_t)b_idx * D_INNER + d) * LSEQ + l]) = v;
                }
            }
        }
    } else {
#pragma unroll
        for (int mi = 0; mi < 4; ++mi) {
#pragma unroll
            for (int ni = 0; ni < 4; ++ni) {
                const int l = l0b + wm * 64 + mi * 16 + (lane >> 4) * 4;
                const int n = n0 + wn * 64 + ni * 16 + (lane & 15);
                float4 v = make_float4(acc[mi][ni][0], acc[mi][ni][1],
                                       acc[mi][ni][2], acc[mi][ni][3]);
                *reinterpret_cast<float4*>(
                    &out0[((size_t)b_idx * D_MODEL + n) * LSEQ + l]) = v;
            }
        }
    }
}

// ---------------- x_proj MFMA GEMM: M=8192 (64-row tiles), N=64 (padded), K=768, 3 segments.
__global__ __launch_bounds__(256) void k_xprojm(const u16* __restrict__ Uhi,
                                                const u16* __restrict__ Ulo,
                                                const u16* __restrict__ Whi,
                                                const u16* __restrict__ Wlo,
                                                float* __restrict__ dbc,
                                                float* __restrict__ bct) {
    __shared__ u16 lA[2][64 * 32];
    __shared__ u16 lB[2][64 * 32];
    const int tid = threadIdx.x;
    const int m0 = blockIdx.x * 64;
    const int arow = tid >> 2, acol = (tid & 3) * 8;

    bf16x8 ra, rb;
    auto load_tile = [&](int t) {
        const int s = t / 24;
        const int ko = (t - s * 24) * 32;
        const u16* Ab = (s < 2) ? Uhi : Ulo;
        const u16* Bb = (s == 1) ? Wlo : Whi;
        ra = *reinterpret_cast<const bf16x8*>(Ab + (size_t)(m0 + arow) * D_INNER + ko + acol);
        rb = *reinterpret_cast<const bf16x8*>(Bb + (size_t)arow * D_INNER + ko + acol);
    };
    auto write_tile = [&](int buf) {
        *reinterpret_cast<bf16x8*>(&lA[buf][arow * 32 + acol]) = ra;
        *reinterpret_cast<bf16x8*>(&lB[buf][arow * 32 + acol]) = rb;
    };

    load_tile(0);
    write_tile(0);
    load_tile(1);

    const int lane = tid & 63, w = tid >> 6;
    const int fr = lane & 15, g = lane >> 4;
    f32x4 acc[4] = {};
    for (int t = 0; t < 72; ++t) {
        const int cur = t & 1;
        __syncthreads();
        bf16x8 a = *reinterpret_cast<const bf16x8*>(&lA[cur][(w * 16 + fr) * 32 + g * 8]);
        bf16x8 b[4];
#pragma unroll
        for (int ni = 0; ni < 4; ++ni)
            b[ni] = *reinterpret_cast<const bf16x8*>(&lB[cur][(ni * 16 + fr) * 32 + g * 8]);
#pragma unroll
        for (int ni = 0; ni < 4; ++ni)
            acc[ni] = __builtin_amdgcn_mfma_f32_16x16x32_bf16(a, b[ni], acc[ni], 0, 0, 0);
        if (t + 1 < 72) {
            __syncthreads();
            write_tile(cur ^ 1);
            if (t + 2 < 72) load_tile(t + 2);
        }
    }

    const int b_idx = m0 >> 10;
#pragma unroll
    for (int ni = 0; ni < 4; ++ni) {
        const int col = ni * 16 + fr;
#pragma unroll
        for (int j = 0; j < 4; ++j) {
            const int r = w * 16 + g * 4 + j;
            const float v = acc[ni][j];
            if (col < DT_RANK) {
                dbc[(size_t)(m0 + r) * DBC_N + col] = v;
            } else if (col < DBC_N) {
                bct[((size_t)b_idx * 32 + (col - DT_RANK)) * LSEQ + ((m0 & 1023) + r)] = v;
            }
        }
    }
}

// ---------------- conv (causal, 3 taps) + SiLU -> uT [b][d][l] f32 + u split bf16 row-major
__global__ __launch_bounds__(256) void k_conv(const float* __restrict__ xin,
                                              const float* __restrict__ cw,
                                              const float* __restrict__ cb,
                                              u16* __restrict__ u_hi,
                                              u16* __restrict__ u_lo,
                                              float* __restrict__ uT) {
    __shared__ float xs[34][32];
    __shared__ float us[32][33];
    const int d0 = blockIdx.x * 32;
    const int l0 = blockIdx.y * 32;
    const int b  = blockIdx.z;
    const int t = threadIdx.x;
    const int dd = t & 31, r = t >> 5;
    for (int rr = r; rr < 34; rr += 8) {
        const int l = l0 - 2 + rr;
        xs[rr][dd] = (l >= 0) ? xin[((size_t)b * LSEQ + l) * D_INNER + d0 + dd] : 0.f;
    }
    __syncthreads();
    const float w0 = cw[(d0 + dd) * 3 + 0], w1 = cw[(d0 + dd) * 3 + 1], w2 = cw[(d0 + dd) * 3 + 2];
    const float bv = cb[d0 + dd];
#pragma unroll
    for (int p = 0; p < 4; ++p) {
        const int li = r + p * 8;
        float acc = bv;
        acc = fmaf(xs[li + 0][dd], w0, acc);
        acc = fmaf(xs[li + 1][dd], w1, acc);
        acc = fmaf(xs[li + 2][dd], w2, acc);
        const float uv = silu(acc);
        u16 h, l;
        split2(uv, h, l);
        const size_t idx = ((size_t)b * LSEQ + l0 + li) * D_INNER + d0 + dd;
        u_hi[idx] = h; u_lo[idx] = l;
        us[li][dd] = uv;
    }
    __syncthreads();
    const int ll = t & 31, dg = t >> 5;
#pragma unroll
    for (int p = 0; p < 4; ++p) {
        const int dl = dg + p * 8;
        uT[((size_t)b * D_INNER + d0 + dl) * LSEQ + l0 + ll] = us[ll][dl];
    }
}

// ---------------- dt_proj (K=24) + softplus -> dtT[b][d][l] (transposed via LDS tile)
__global__ __launch_bounds__(256) void k_dtproj(const float* __restrict__ dbc,
                                                const float* __restrict__ W,
                                                const float* __restrict__ bias,
                                                float* __restrict__ dtT) {
    __shared__ float sd[64][25];
    __shared__ float sw[64][24];
    __shared__ float sb[64];
    const int d0 = blockIdx.x * 64;
    const int row0 = blockIdx.y * 64;
    const int b = row0 >> 10, lr0 = row0 & 1023;
    const int t = threadIdx.x;
    for (int e = t; e < 64 * 24; e += 256) {
        const int rl = e / 24, rr = e - rl * 24;
        sd[rl][rr] = dbc[(size_t)(row0 + rl) * DBC_N + rr];
        sw[rl][rr] = W[(size_t)(d0 + rl) * DT_RANK + rr];
    }
    if (t < 64) sb[t] = bias[d0 + t];
    __syncthreads();
    const int ll = t & 63, dg = t >> 6;
    for (int dd = 0; dd < 16; ++dd) {
        const int dl = dg * 16 + dd;
        float acc = sb[dl];
#pragma unroll
        for (int r = 0; r < DT_RANK; ++r) acc = fmaf(sd[ll][r], sw[dl][r], acc);
        const float v = (acc > 20.f) ? acc : log1pf(__expf(acc));
        dtT[((size_t)b * D_INNER + d0 + dl) * LSEQ + lr0 + ll] = v;
    }
}

// ---------------- block-parallel selective scan, v4.
// Pass A keeps per-step running product Pi[l] and local state hloc[l] in regs.
// Linear recurrence => true state h[l] = prefH*Pi[l] + hloc[l]: pass C has NO
// exp and NO serial chain (independent per step). n-reduce via DPP row_ror.
__global__ __launch_bounds__(1024, 4) void k_scan(float* dtyT,
                                                  const float* __restrict__ uT,
                                                  const float* __restrict__ szT,
                                                  const float* __restrict__ bct,
                                                  const float* __restrict__ A_log,
                                                  const float* __restrict__ Dp) {
    __shared__ float dt_s[LSEQ], u_s[LSEQ], sz_s[LSEQ], y_s[LSEQ];
    __shared__ float Pb[16][NSEG + 2], Hb[16][NSEG + 2];
    const int t = threadIdx.x;
    const int d = blockIdx.x;
    const int b = blockIdx.y;
    const size_t base = ((size_t)b * D_INNER + d) * LSEQ;
    if (t < 256) {
        *reinterpret_cast<float4*>(&dt_s[t * 4]) =
            *reinterpret_cast<const float4*>(&dtyT[base + t * 4]);
    } else if (t < 512) {
        const int q = (t - 256) * 4;
        *reinterpret_cast<float4*>(&u_s[q]) = *reinterpret_cast<const float4*>(&uT[base + q]);
    } else if (t < 768) {
        const int q = (t - 512) * 4;
        *reinterpret_cast<float4*>(&sz_s[q]) = *reinterpret_cast<const float4*>(&szT[base + q]);
    }
    const int n = t & 15, seg = t >> 4;
    const float Aval = -__expf(A_log[d * D_STATE + n]);
    const float Dv = Dp[d];
    float Breg[SEG];
    {
        const size_t bb = ((size_t)b * 32 + n) * LSEQ + seg * SEG;
#pragma unroll
        for (int q = 0; q < SEG; q += 4)
            *reinterpret_cast<float4*>(&Breg[q]) = *reinterpret_cast<const float4*>(&bct[bb + q]);
    }
    __syncthreads();
    const int l0 = seg * SEG;
    // pass A: running (P,h), keeping per-step values in registers
    float Pi[SEG], hloc[SEG];
    float h = 0.f, P = 1.f;
#pragma unroll
    for (int l = 0; l < SEG; ++l) {
        const float dtv = dt_s[l0 + l];
        const float a = __expf(dtv * Aval);
        P *= a;
        Pi[l] = P;
        h = fmaf(a, h, dtv * u_s[l0 + l] * Breg[l]);
        hloc[l] = h;
    }
    Pb[n][seg] = P;
    Hb[n][seg] = h;
    // deferred Creg load: latency hides under the scan phase below
    float Creg[SEG];
    {
        const size_t cc = ((size_t)b * 32 + 16 + n) * LSEQ + seg * SEG;
#pragma unroll
        for (int q = 0; q < SEG; q += 4)
            *reinterpret_cast<float4*>(&Creg[q]) = *reinterpret_cast<const float4*>(&bct[cc + q]);
    }
    __syncthreads();
    // in-wave inclusive scan: wave w owns state n=w, lane = segment index
    {
        const int w = t >> 6, lane = t & 63;
        float Pw = Pb[w][lane], Hw = Hb[w][lane];
#pragma unroll
        for (int off = 1; off < NSEG; off <<= 1) {
            const float Pp = __shfl_up(Pw, off);
            const float Hp = __shfl_up(Hw, off);
            if (lane >= off) {
                Hw = fmaf(Hp, Pw, Hw);
                Pw *= Pp;
            }
        }
        Hb[w][lane] = Hw;
    }
    __syncthreads();
    // pass C: h[l] = prefH*Pi[l] + hloc[l]; independent per step
    const float prefH = (seg == 0) ? 0.f : Hb[n][seg - 1];
#pragma unroll
    for (int l = 0; l < SEG; ++l) {
        const float ht = fmaf(prefH, Pi[l], hloc[l]);
        float p = ht * Creg[l];
        p += dpp_mov<0x128>(p);   // row_ror:8
        p += dpp_mov<0x124>(p);   // row_ror:4
        p += dpp_mov<0x122>(p);   // row_ror:2
        p += dpp_mov<0x121>(p);   // row_ror:1
        if (n == 0) {
            const float u_v = u_s[l0 + l];
            y_s[l0 + l] = fmaf(u_v, Dv, p) * sz_s[l0 + l];
        }
    }
    __syncthreads();
    if (t < 256)
        *reinterpret_cast<float4*>(&dtyT[base + t * 4]) =
            *reinterpret_cast<const float4*>(&y_s[t * 4]);
}

extern "C" void kernel_launch(void* const* d_in, const int* in_sizes, int n_in,
                              void* d_out, int out_size, void* d_ws, size_t ws_size,
                              hipStream_t stream) {
    const float* x         = (const float*)d_in[0];
    const float* in_proj_w = (const float*)d_in[1];
    const float* conv_w    = (const float*)d_in[2];
    const float* conv_b    = (const float*)d_in[3];
    const float* x_proj_w  = (const float*)d_in[4];
    const float* dt_proj_w = (const float*)d_in[5];
    const float* dt_proj_b = (const float*)d_in[6];
    const float* A_log     = (const float*)d_in[7];
    const float* Dp        = (const float*)d_in[8];
    const float* out_proj_w= (const float*)d_in[9];
    float* out = (float*)d_out;

    const size_t SB = (size_t)NROWS * D_INNER * 4;   // 25.2 MB
    char* wsb = (char*)d_ws;
    float* xin   = (float*)(wsb);                    // R0: xin, then dtT/y
    float* szT   = (float*)(wsb + SB);               // R1
    u16*  u_hi   = (u16*)  (wsb + 2 * SB);           // R2: u split bf16
    u16*  u_lo   = u_hi + (size_t)NROWS * D_INNER;
    float* uT    = (float*)(wsb + 3 * SB);           // R3: Ax split, then uT, then Ay split
    float* dbc   = (float*)(wsb + 4 * SB);
    float* bct   = (float*)(wsb + 4 * SB + 1835008);
    u16*  Wi_hi  = (u16*) (wsb + 4 * SB + 1835008 + 1048576);
    u16*  Wi_lo  = Wi_hi + 1536 * 384;
    u16*  Wo_hi  = Wi_lo + 1536 * 384;
    u16*  Wo_lo  = Wo_hi + 384 * 768;
    u16*  Wx_hi  = Wo_lo + 384 * 768;
    u16*  Wx_lo  = Wx_hi + 64 * 768;
    u16*  Ax_hi  = (u16*)uT;                 // dead before conv writes uT
    u16*  Ax_lo  = Ax_hi + (size_t)NROWS * 384;
    u16*  Ay_hi  = (u16*)uT;                 // uT dead after scan
    u16*  Ay_lo  = Ay_hi + (size_t)NROWS * 768;
    float* dtyT  = xin;                      // xin dead after conv; dt then y in place

    k_splitw<<<(1536 * 384 + 255) / 256, 256, 0, stream>>>(in_proj_w, Wi_hi, Wi_lo, 1536 * 384);
    k_splitw<<<(384 * 768 + 255) / 256, 256, 0, stream>>>(out_proj_w, Wo_hi, Wo_lo, 384 * 768);
    k_splitw_pad<<<(64 * 768 + 255) / 256, 256, 0, stream>>>(x_proj_w, Wx_hi, Wx_lo);
    k_splitT<<<dim3(12, 32, NB), 256, 0, stream>>>(x, Ax_hi, Ax_lo, 384);
    k_gemm<384, 0><<<dim3(12, 64), 256, 0, stream>>>(Ax_hi, Ax_lo, Wi_hi, Wi_lo, xin, szT);
    k_conv<<<dim3(24, 32, NB), 256, 0, stream>>>(xin, conv_w, conv_b, u_hi, u_lo, uT);
    k_xprojm<<<NROWS / 64, 256, 0, stream>>>(u_hi, u_lo, Wx_hi, Wx_lo, dbc, bct);
    k_dtproj<<<dim3(12, NROWS / 64), 256, 0, stream>>>(dbc, dt_proj_w, dt_proj_b, dtyT);
    k_scan<<<dim3(D_INNER, NB), 1024, 0, stream>>>(dtyT, uT, szT, bct, A_log, Dp);
    k_splitT<<<dim3(24, 32, NB), 256, 0, stream>>>(dtyT, Ay_hi, Ay_lo, 768);
    k_gemm<768, 1><<<dim3(3, 64), 256, 0, stream>>>(Ay_hi, Ay_lo, Wo_hi, Wo_lo, out, nullptr);
}

// Round 9
// 288.074 us; speedup vs baseline: 1.2234x; 1.2234x over previous
//
#include <hip/hip_runtime.h>

#define D_MODEL 384
#define D_STATE 16
#define D_INNER 768
#define DT_RANK 24
#define NB 8
#define LSEQ 1024
#define NROWS (NB * LSEQ)             // 8192
#define DBC_N 56
#define SEG 16
#define NSEG 64

typedef unsigned short u16;
typedef __attribute__((ext_vector_type(8))) short bf16x8;
typedef __attribute__((ext_vector_type(4))) float f32x4;

__device__ __forceinline__ float silu(float x) { return x / (1.f + __expf(-x)); }

__device__ __forceinline__ u16 f2bf_rne(float v, float& hval) {
    unsigned u = __builtin_bit_cast(unsigned, v);
    unsigned h = (u + 0x7FFFu + ((u >> 16) & 1u)) >> 16;
    hval = __builtin_bit_cast(float, h << 16);
    return (u16)h;
}

__device__ __forceinline__ void split2(float v, u16& h, u16& l) {
    float hval, dummy;
    h = f2bf_rne(v, hval);
    l = f2bf_rne(v - hval, dummy);
}

// DPP move within rows of 16 lanes (VALU, no DS pipe). CTRL 0x120+N = row_ror:N.
template <int CTRL>
__device__ __forceinline__ float dpp_mov(float v) {
    return __builtin_bit_cast(float, __builtin_amdgcn_update_dpp(
        0, __builtin_bit_cast(int, v), CTRL, 0xf, 0xf, false));
}

// ---------------- weight split: f32 -> bf16 hi/lo
__global__ __launch_bounds__(256) void k_splitw(const float* __restrict__ src,
                                                u16* __restrict__ hi, u16* __restrict__ lo,
                                                int count) {
    const int i = blockIdx.x * 256 + threadIdx.x;
    if (i >= count) return;
    u16 h, l;
    split2(src[i], h, l);
    hi[i] = h; lo[i] = l;
}

// ---------------- x_proj weight split, padded 56 -> 64 rows (zeros)
__global__ __launch_bounds__(256) void k_splitw_pad(const float* __restrict__ src,
                                                    u16* __restrict__ hi, u16* __restrict__ lo) {
    const int i = blockIdx.x * 256 + threadIdx.x;   // over 64*768
    if (i >= 64 * 768) return;
    const int row = i / 768;
    u16 h = 0, l = 0;
    if (row < DBC_N) split2(src[i], h, l);
    hi[i] = h; lo[i] = l;
}

// ---------------- activation split + transpose: src [B][R][1024] f32 -> hi/lo [B*1024][R] bf16
__global__ __launch_bounds__(256) void k_splitT(const float* __restrict__ src,
                                                u16* __restrict__ hi, u16* __restrict__ lo,
                                                int R) {
    __shared__ float s[32][33];
    const int r0 = blockIdx.x * 32, c0 = blockIdx.y * 32, b = blockIdx.z;
    const int t = threadIdx.x;
    const int cc = t & 31, rr = t >> 5;
#pragma unroll
    for (int p = 0; p < 4; ++p)
        s[rr + p * 8][cc] = src[((size_t)b * R + r0 + rr + p * 8) * LSEQ + c0 + cc];
    __syncthreads();
    const int rr2 = t & 31, cc2 = t >> 5;
#pragma unroll
    for (int p = 0; p < 4; ++p) {
        const int c = cc2 + p * 8;
        u16 h, l;
        split2(s[rr2][c], h, l);
        const size_t idx = ((size_t)b * LSEQ + c0 + c) * R + r0 + rr2;
        hi[idx] = h; lo[idx] = l;
    }
}

// ---------------- split-bf16 MFMA GEMM (128x128 tile), k-tile outer / 3-term inner.
// Stages A-hi/A-lo/B-hi/B-lo ONCE per k-tile (64 KB LDS), 48 MFMA per barrier pair.
// MODE 0: in_proj epilogue; MODE 1: out_proj epilogue
template <int K, int MODE>
__global__ __launch_bounds__(256) void k_gemm(const u16* __restrict__ Ahi,
                                              const u16* __restrict__ Alo,
                                              const u16* __restrict__ Bhi,
                                              const u16* __restrict__ Blo,
                                              float* __restrict__ out0,
                                              float* __restrict__ out1) {
    constexpr int KT = K / 32;
    __shared__ u16 lA[2][2][512 * 8];   // [dbuf][hi/lo]
    __shared__ u16 lB[2][2][512 * 8];
    const int tid = threadIdx.x;
    const int n0 = blockIdx.x * 128;
    const int m0 = blockIdx.y * 128;

    bf16x8 rah[2], ral[2], rbh[2], rbl[2];
    auto load_kt = [&](int kt) {
        const int ko = kt * 32;
#pragma unroll
        for (int i = 0; i < 2; ++i) {
            const int slot = tid + 256 * i;
            const size_t aoff = (size_t)(m0 + (slot & 127)) * K + ko + (slot >> 7) * 8;
            const size_t boff = (size_t)(n0 + (slot & 127)) * K + ko + (slot >> 7) * 8;
            rah[i] = *reinterpret_cast<const bf16x8*>(Ahi + aoff);
            ral[i] = *reinterpret_cast<const bf16x8*>(Alo + aoff);
            rbh[i] = *reinterpret_cast<const bf16x8*>(Bhi + boff);
            rbl[i] = *reinterpret_cast<const bf16x8*>(Blo + boff);
        }
    };
    auto write_kt = [&](int buf) {
#pragma unroll
        for (int i = 0; i < 2; ++i) {
            const int slot = tid + 256 * i;
            *reinterpret_cast<bf16x8*>(&lA[buf][0][slot * 8]) = rah[i];
            *reinterpret_cast<bf16x8*>(&lA[buf][1][slot * 8]) = ral[i];
            *reinterpret_cast<bf16x8*>(&lB[buf][0][slot * 8]) = rbh[i];
            *reinterpret_cast<bf16x8*>(&lB[buf][1][slot * 8]) = rbl[i];
        }
    };

    load_kt(0);
    write_kt(0);
    if (KT > 1) load_kt(1);

    const int lane = tid & 63, w = tid >> 6;
    const int wm = w >> 1, wn = w & 1;
    const int fr = lane & 15, g = lane >> 4;
    const int abase = (g * 128 + wm * 64 + fr) * 8;
    const int bbase = (g * 128 + wn * 64 + fr) * 8;

    f32x4 acc[4][4] = {};
    for (int kt = 0; kt < KT; ++kt) {
        const int cur = kt & 1;
        __syncthreads();
        bf16x8 ah[4], al[4], bh[4], bl[4];
#pragma unroll
        for (int mi = 0; mi < 4; ++mi) {
            ah[mi] = *reinterpret_cast<const bf16x8*>(&lA[cur][0][abase + mi * 128]);
            al[mi] = *reinterpret_cast<const bf16x8*>(&lA[cur][1][abase + mi * 128]);
        }
#pragma unroll
        for (int ni = 0; ni < 4; ++ni) {
            bh[ni] = *reinterpret_cast<const bf16x8*>(&lB[cur][0][bbase + ni * 128]);
            bl[ni] = *reinterpret_cast<const bf16x8*>(&lB[cur][1][bbase + ni * 128]);
        }
#pragma unroll
        for (int mi = 0; mi < 4; ++mi)
#pragma unroll
            for (int ni = 0; ni < 4; ++ni) {
                acc[mi][ni] = __builtin_amdgcn_mfma_f32_16x16x32_bf16(
                    ah[mi], bh[ni], acc[mi][ni], 0, 0, 0);
                acc[mi][ni] = __builtin_amdgcn_mfma_f32_16x16x32_bf16(
                    ah[mi], bl[ni], acc[mi][ni], 0, 0, 0);
                acc[mi][ni] = __builtin_amdgcn_mfma_f32_16x16x32_bf16(
                    al[mi], bh[ni], acc[mi][ni], 0, 0, 0);
            }
        if (kt + 1 < KT) {
            __syncthreads();
            write_kt(cur ^ 1);
            if (kt + 2 < KT) load_kt(kt + 2);
        }
    }

    const int b_idx = m0 >> 10;
    const int l0b = m0 & 1023;
    if (MODE == 0) {
        if (n0 < D_INNER) {
#pragma unroll
            for (int mi = 0; mi < 4; ++mi) {
#pragma unroll
                for (int ni = 0; ni < 4; ++ni) {
                    const int m = m0 + wm * 64 + mi * 16 + (lane >> 4) * 4;
                    const int n = n0 + wn * 64 + ni * 16 + (lane & 15);
#pragma unroll
                    for (int j = 0; j < 4; ++j)
                        out0[(size_t)(m + j) * D_INNER + n] = acc[mi][ni][j];
                }
            }
        } else {
#pragma unroll
            for (int mi = 0; mi < 4; ++mi) {
#pragma unroll
                for (int ni = 0; ni < 4; ++ni) {
                    const int l = l0b + wm * 64 + mi * 16 + (lane >> 4) * 4;
                    const int d = (n0 - D_INNER) + wn * 64 + ni * 16 + (lane & 15);
                    float4 v = make_float4(silu(acc[mi][ni][0]), silu(acc[mi][ni][1]),
                                           silu(acc[mi][ni][2]), silu(acc[mi][ni][3]));
                    *reinterpret_cast<float4*>(
                        &out1[((size_t)b_idx * D_INNER + d) * LSEQ + l]) = v;
                }
            }
        }
    } else {
#pragma unroll
        for (int mi = 0; mi < 4; ++mi) {
#pragma unroll
            for (int ni = 0; ni < 4; ++ni) {
                const int l = l0b + wm * 64 + mi * 16 + (lane >> 4) * 4;
                const int n = n0 + wn * 64 + ni * 16 + (lane & 15);
                float4 v = make_float4(acc[mi][ni][0], acc[mi][ni][1],
                                       acc[mi][ni][2], acc[mi][ni][3]);
                *reinterpret_cast<float4*>(
                    &out0[((size_t)b_idx * D_MODEL + n) * LSEQ + l]) = v;
            }
        }
    }
}

// ---------------- x_proj MFMA GEMM: M=8192 (64-row tiles), N=64 (padded), K=768,
// k-tile outer / 3-term inner (stages hi+lo once per k-tile).
__global__ __launch_bounds__(256) void k_xprojm(const u16* __restrict__ Uhi,
                                                const u16* __restrict__ Ulo,
                                                const u16* __restrict__ Whi,
                                                const u16* __restrict__ Wlo,
                                                float* __restrict__ dbc,
                                                float* __restrict__ bct) {
    __shared__ u16 lA[2][2][64 * 32];
    __shared__ u16 lB[2][2][64 * 32];
    const int tid = threadIdx.x;
    const int m0 = blockIdx.x * 64;
    const int arow = tid >> 2, acol = (tid & 3) * 8;

    bf16x8 rah, ral, rbh, rbl;
    auto load_kt = [&](int kt) {
        const int ko = kt * 32;
        const size_t aoff = (size_t)(m0 + arow) * D_INNER + ko + acol;
        const size_t boff = (size_t)arow * D_INNER + ko + acol;
        rah = *reinterpret_cast<const bf16x8*>(Uhi + aoff);
        ral = *reinterpret_cast<const bf16x8*>(Ulo + aoff);
        rbh = *reinterpret_cast<const bf16x8*>(Whi + boff);
        rbl = *reinterpret_cast<const bf16x8*>(Wlo + boff);
    };
    auto write_kt = [&](int buf) {
        *reinterpret_cast<bf16x8*>(&lA[buf][0][arow * 32 + acol]) = rah;
        *reinterpret_cast<bf16x8*>(&lA[buf][1][arow * 32 + acol]) = ral;
        *reinterpret_cast<bf16x8*>(&lB[buf][0][arow * 32 + acol]) = rbh;
        *reinterpret_cast<bf16x8*>(&lB[buf][1][arow * 32 + acol]) = rbl;
    };

    load_kt(0);
    write_kt(0);
    load_kt(1);

    const int lane = tid & 63, w = tid >> 6;
    const int fr = lane & 15, g = lane >> 4;
    f32x4 acc[4] = {};
    for (int kt = 0; kt < 24; ++kt) {
        const int cur = kt & 1;
        __syncthreads();
        const int af = (w * 16 + fr) * 32 + g * 8;
        bf16x8 ah = *reinterpret_cast<const bf16x8*>(&lA[cur][0][af]);
        bf16x8 al = *reinterpret_cast<const bf16x8*>(&lA[cur][1][af]);
        bf16x8 bh[4], bl[4];
#pragma unroll
        for (int ni = 0; ni < 4; ++ni) {
            const int bf = (ni * 16 + fr) * 32 + g * 8;
            bh[ni] = *reinterpret_cast<const bf16x8*>(&lB[cur][0][bf]);
            bl[ni] = *reinterpret_cast<const bf16x8*>(&lB[cur][1][bf]);
        }
#pragma unroll
        for (int ni = 0; ni < 4; ++ni) {
            acc[ni] = __builtin_amdgcn_mfma_f32_16x16x32_bf16(ah, bh[ni], acc[ni], 0, 0, 0);
            acc[ni] = __builtin_amdgcn_mfma_f32_16x16x32_bf16(ah, bl[ni], acc[ni], 0, 0, 0);
            acc[ni] = __builtin_amdgcn_mfma_f32_16x16x32_bf16(al, bh[ni], acc[ni], 0, 0, 0);
        }
        if (kt + 1 < 24) {
            __syncthreads();
            write_kt(cur ^ 1);
            if (kt + 2 < 24) load_kt(kt + 2);
        }
    }

    const int b_idx = m0 >> 10;
#pragma unroll
    for (int ni = 0; ni < 4; ++ni) {
        const int col = ni * 16 + fr;
#pragma unroll
        for (int j = 0; j < 4; ++j) {
            const int r = w * 16 + g * 4 + j;
            const float v = acc[ni][j];
            if (col < DT_RANK) {
                dbc[(size_t)(m0 + r) * DBC_N + col] = v;
            } else if (col < DBC_N) {
                bct[((size_t)b_idx * 32 + (col - DT_RANK)) * LSEQ + ((m0 & 1023) + r)] = v;
            }
        }
    }
}

// ---------------- conv (causal, 3 taps) + SiLU -> uT [b][d][l] f32 + u split bf16 row-major
__global__ __launch_bounds__(256) void k_conv(const float* __restrict__ xin,
                                              const float* __restrict__ cw,
                                              const float* __restrict__ cb,
                                              u16* __restrict__ u_hi,
                                              u16* __restrict__ u_lo,
                                              float* __restrict__ uT) {
    __shared__ float xs[34][32];
    __shared__ float us[32][33];
    const int d0 = blockIdx.x * 32;
    const int l0 = blockIdx.y * 32;
    const int b  = blockIdx.z;
    const int t = threadIdx.x;
    const int dd = t & 31, r = t >> 5;
    for (int rr = r; rr < 34; rr += 8) {
        const int l = l0 - 2 + rr;
        xs[rr][dd] = (l >= 0) ? xin[((size_t)b * LSEQ + l) * D_INNER + d0 + dd] : 0.f;
    }
    __syncthreads();
    const float w0 = cw[(d0 + dd) * 3 + 0], w1 = cw[(d0 + dd) * 3 + 1], w2 = cw[(d0 + dd) * 3 + 2];
    const float bv = cb[d0 + dd];
#pragma unroll
    for (int p = 0; p < 4; ++p) {
        const int li = r + p * 8;
        float acc = bv;
        acc = fmaf(xs[li + 0][dd], w0, acc);
        acc = fmaf(xs[li + 1][dd], w1, acc);
        acc = fmaf(xs[li + 2][dd], w2, acc);
        const float uv = silu(acc);
        u16 h, l;
        split2(uv, h, l);
        const size_t idx = ((size_t)b * LSEQ + l0 + li) * D_INNER + d0 + dd;
        u_hi[idx] = h; u_lo[idx] = l;
        us[li][dd] = uv;
    }
    __syncthreads();
    const int ll = t & 31, dg = t >> 5;
#pragma unroll
    for (int p = 0; p < 4; ++p) {
        const int dl = dg + p * 8;
        uT[((size_t)b * D_INNER + d0 + dl) * LSEQ + l0 + ll] = us[ll][dl];
    }
}

// ---------------- dt_proj (K=24) + softplus -> dtT[b][d][l] (transposed via LDS tile)
__global__ __launch_bounds__(256) void k_dtproj(const float* __restrict__ dbc,
                                                const float* __restrict__ W,
                                                const float* __restrict__ bias,
                                                float* __restrict__ dtT) {
    __shared__ float sd[64][25];
    __shared__ float sw[64][24];
    __shared__ float sb[64];
    const int d0 = blockIdx.x * 64;
    const int row0 = blockIdx.y * 64;
    const int b = row0 >> 10, lr0 = row0 & 1023;
    const int t = threadIdx.x;
    for (int e = t; e < 64 * 24; e += 256) {
        const int rl = e / 24, rr = e - rl * 24;
        sd[rl][rr] = dbc[(size_t)(row0 + rl) * DBC_N + rr];
        sw[rl][rr] = W[(size_t)(d0 + rl) * DT_RANK + rr];
    }
    if (t < 64) sb[t] = bias[d0 + t];
    __syncthreads();
    const int ll = t & 63, dg = t >> 6;
    for (int dd = 0; dd < 16; ++dd) {
        const int dl = dg * 16 + dd;
        float acc = sb[dl];
#pragma unroll
        for (int r = 0; r < DT_RANK; ++r) acc = fmaf(sd[ll][r], sw[dl][r], acc);
        const float v = (acc > 20.f) ? acc : log1pf(__expf(acc));
        dtT[((size_t)b * D_INNER + d0 + dl) * LSEQ + lr0 + ll] = v;
    }
}

// ---------------- block-parallel selective scan (R7 v3, proven 108 us).
// Pass A: per-segment (P,H). Segment scan: IN-WAVE (wave w scans the 64
// segments of state n=w via shfl_up, no barriers). Pass C: n-reduction via
// DPP row_ror rotate-reduce (pure VALU, zero DS ops). 4 barriers total.
__global__ __launch_bounds__(1024, 8) void k_scan(float* dtyT,
                                                  const float* __restrict__ uT,
                                                  const float* __restrict__ szT,
                                                  const float* __restrict__ bct,
                                                  const float* __restrict__ A_log,
                                                  const float* __restrict__ Dp) {
    __shared__ float dt_s[LSEQ], u_s[LSEQ], sz_s[LSEQ], y_s[LSEQ];
    __shared__ float Pb[16][NSEG + 2], Hb[16][NSEG + 2];
    const int t = threadIdx.x;
    const int d = blockIdx.x;
    const int b = blockIdx.y;
    const size_t base = ((size_t)b * D_INNER + d) * LSEQ;
    if (t < 256) {
        *reinterpret_cast<float4*>(&dt_s[t * 4]) =
            *reinterpret_cast<const float4*>(&dtyT[base + t * 4]);
    } else if (t < 512) {
        const int q = (t - 256) * 4;
        *reinterpret_cast<float4*>(&u_s[q]) = *reinterpret_cast<const float4*>(&uT[base + q]);
    } else if (t < 768) {
        const int q = (t - 512) * 4;
        *reinterpret_cast<float4*>(&sz_s[q]) = *reinterpret_cast<const float4*>(&szT[base + q]);
    }
    const int n = t & 15, seg = t >> 4;
    const float Aval = -__expf(A_log[d * D_STATE + n]);
    const float Dv = Dp[d];
    float Breg[SEG];
    {
        const size_t bb = ((size_t)b * 32 + n) * LSEQ + seg * SEG;
#pragma unroll
        for (int q = 0; q < SEG; q += 4)
            *reinterpret_cast<float4*>(&Breg[q]) = *reinterpret_cast<const float4*>(&bct[bb + q]);
    }
    __syncthreads();
    const int l0 = seg * SEG;
    // pass A: segment-local transform (P, H)
    float h = 0.f, P = 1.f;
#pragma unroll
    for (int l = 0; l < SEG; ++l) {
        const float dtv = dt_s[l0 + l];
        const float a = __expf(dtv * Aval);
        h = fmaf(a, h, dtv * u_s[l0 + l] * Breg[l]);
        P *= a;
    }
    Pb[n][seg] = P;
    Hb[n][seg] = h;
    // deferred Creg load: latency hides under the scan phase below
    float Creg[SEG];
    {
        const size_t cc = ((size_t)b * 32 + 16 + n) * LSEQ + seg * SEG;
#pragma unroll
        for (int q = 0; q < SEG; q += 4)
            *reinterpret_cast<float4*>(&Creg[q]) = *reinterpret_cast<const float4*>(&bct[cc + q]);
    }
    __syncthreads();
    // in-wave inclusive scan: wave w owns state n=w, lane = segment index
    {
        const int w = t >> 6, lane = t & 63;
        float Pw = Pb[w][lane], Hw = Hb[w][lane];
#pragma unroll
        for (int off = 1; off < NSEG; off <<= 1) {
            const float Pp = __shfl_up(Pw, off);
            const float Hp = __shfl_up(Hw, off);
            if (lane >= off) {
                Hw = fmaf(Hp, Pw, Hw);
                Pw *= Pp;
            }
        }
        Hb[w][lane] = Hw;
    }
    __syncthreads();
    // pass C: exact prefix; n-reduce via DPP rotate within rows of 16
    h = (seg == 0) ? 0.f : Hb[n][seg - 1];
#pragma unroll
    for (int l = 0; l < SEG; ++l) {
        const float dtv = dt_s[l0 + l];
        const float u_v = u_s[l0 + l];
        const float a = __expf(dtv * Aval);
        h = fmaf(a, h, dtv * u_v * Breg[l]);
        float p = h * Creg[l];
        p += dpp_mov<0x128>(p);   // row_ror:8
        p += dpp_mov<0x124>(p);   // row_ror:4
        p += dpp_mov<0x122>(p);   // row_ror:2
        p += dpp_mov<0x121>(p);   // row_ror:1
        if (n == 0)
            y_s[l0 + l] = fmaf(u_v, Dv, p) * sz_s[l0 + l];
    }
    __syncthreads();
    if (t < 256)
        *reinterpret_cast<float4*>(&dtyT[base + t * 4]) =
            *reinterpret_cast<const float4*>(&y_s[t * 4]);
}

extern "C" void kernel_launch(void* const* d_in, const int* in_sizes, int n_in,
                              void* d_out, int out_size, void* d_ws, size_t ws_size,
                              hipStream_t stream) {
    const float* x         = (const float*)d_in[0];
    const float* in_proj_w = (const float*)d_in[1];
    const float* conv_w    = (const float*)d_in[2];
    const float* conv_b    = (const float*)d_in[3];
    const float* x_proj_w  = (const float*)d_in[4];
    const float* dt_proj_w = (const float*)d_in[5];
    const float* dt_proj_b = (const float*)d_in[6];
    const float* A_log     = (const float*)d_in[7];
    const float* Dp        = (const float*)d_in[8];
    const float* out_proj_w= (const float*)d_in[9];
    float* out = (float*)d_out;

    const size_t SB = (size_t)NROWS * D_INNER * 4;   // 25.2 MB
    char* wsb = (char*)d_ws;
    float* xin   = (float*)(wsb);                    // R0: xin, then dtT/y
    float* szT   = (float*)(wsb + SB);               // R1
    u16*  u_hi   = (u16*)  (wsb + 2 * SB);           // R2: u split bf16
    u16*  u_lo   = u_hi + (size_t)NROWS * D_INNER;
    float* uT    = (float*)(wsb + 3 * SB);           // R3: Ax split, then uT, then Ay split
    float* dbc   = (float*)(wsb + 4 * SB);
    float* bct   = (float*)(wsb + 4 * SB + 1835008);
    u16*  Wi_hi  = (u16*) (wsb + 4 * SB + 1835008 + 1048576);
    u16*  Wi_lo  = Wi_hi + 1536 * 384;
    u16*  Wo_hi  = Wi_lo + 1536 * 384;
    u16*  Wo_lo  = Wo_hi + 384 * 768;
    u16*  Wx_hi  = Wo_lo + 384 * 768;
    u16*  Wx_lo  = Wx_hi + 64 * 768;
    u16*  Ax_hi  = (u16*)uT;                 // dead before conv writes uT
    u16*  Ax_lo  = Ax_hi + (size_t)NROWS * 384;
    u16*  Ay_hi  = (u16*)uT;                 // uT dead after scan
    u16*  Ay_lo  = Ay_hi + (size_t)NROWS * 768;
    float* dtyT  = xin;                      // xin dead after conv; dt then y in place

    k_splitw<<<(1536 * 384 + 255) / 256, 256, 0, stream>>>(in_proj_w, Wi_hi, Wi_lo, 1536 * 384);
    k_splitw<<<(384 * 768 + 255) / 256, 256, 0, stream>>>(out_proj_w, Wo_hi, Wo_lo, 384 * 768);
    k_splitw_pad<<<(64 * 768 + 255) / 256, 256, 0, stream>>>(x_proj_w, Wx_hi, Wx_lo);
    k_splitT<<<dim3(12, 32, NB), 256, 0, stream>>>(x, Ax_hi, Ax_lo, 384);
    k_gemm<384, 0><<<dim3(12, 64), 256, 0, stream>>>(Ax_hi, Ax_lo, Wi_hi, Wi_lo, xin, szT);
    k_conv<<<dim3(24, 32, NB), 256, 0, stream>>>(xin, conv_w, conv_b, u_hi, u_lo, uT);
    k_xprojm<<<NROWS / 64, 256, 0, stream>>>(u_hi, u_lo, Wx_hi, Wx_lo, dbc, bct);
    k_dtproj<<<dim3(12, NROWS / 64), 256, 0, stream>>>(dbc, dt_proj_w, dt_proj_b, dtyT);
    k_scan<<<dim3(D_INNER, NB), 1024, 0, stream>>>(dtyT, uT, szT, bct, A_log, Dp);
    k_splitT<<<dim3(24, 32, NB), 256, 0, stream>>>(dtyT, Ay_hi, Ay_lo, 768);
    k_gemm<768, 1><<<dim3(3, 64), 256, 0, stream>>>(Ay_hi, Ay_lo, Wo_hi, Wo_lo, out, nullptr);
}